// Round 3
// baseline (324.515 us; speedup 1.0000x reference)
//
#include <hip/hip_runtime.h>

// Problem constants (from reference file). FLOAT32 problem (threshold arithmetic
// shows no bf16 eps floor -> inputs/output are fp32 as the reference declares).
constexpr int N = 50000;      // nodes
constexpr int E = 800000;     // edges
constexpr int D = 64;         // feature dim == wave width
constexpr int DOUT = 320;     // (4+1)*64 output feature dim
constexpr int SCAN_BLOCKS = (N + 255) / 256;   // 196

// ---------------- index dtype detection (int64 vs int32) ----------------
// If edge_index is little-endian int64 with values in [0, 50000), every odd
// 32-bit word of the first 128 entries is 0. False-positive prob ~(1/50000)^128.
__global__ void detect_kernel(const int* __restrict__ ei32, int* __restrict__ flag) {
    if (blockIdx.x == 0 && threadIdx.x == 0) {
        int s = 0;
        for (int k = 0; k < 128; ++k) s |= ei32[2 * k + 1];
        *flag = (s == 0) ? 1 : 0;
    }
}

__device__ __forceinline__ int load_src(const int* ei32, int is64, int i) {
    return is64 ? ei32[2 * i] : ei32[i];
}
__device__ __forceinline__ int load_dst(const int* ei32, int is64, int i) {
    return is64 ? ei32[2 * (E + i)] : ei32[E + i];
}

// ---------------- CSR build ----------------

__global__ __launch_bounds__(256) void hist_kernel(const int* __restrict__ ei32,
                                                   const int* __restrict__ flag,
                                                   int* __restrict__ cnt) {
    int i = blockIdx.x * 256 + threadIdx.x;
    int is64 = *flag;
    if (i < E) atomicAdd(&cnt[load_dst(ei32, is64, i)], 1);
}

__global__ __launch_bounds__(256) void scan1_kernel(const int* __restrict__ cnt,
                                                    int* __restrict__ offs,
                                                    int* __restrict__ P) {
    __shared__ int sm[256];
    int t = threadIdx.x;
    int i = blockIdx.x * 256 + t;
    int v = (i < N) ? cnt[i] : 0;
    sm[t] = v; __syncthreads();
    for (int o = 1; o < 256; o <<= 1) {
        int u = (t >= o) ? sm[t - o] : 0;
        __syncthreads();
        sm[t] += u;
        __syncthreads();
    }
    if (i < N) offs[i] = sm[t] - v;         // tile-local exclusive
    if (t == 255) P[blockIdx.x] = sm[255];  // tile total
}

__global__ __launch_bounds__(256) void scan2_kernel(int* __restrict__ P,
                                                    int* __restrict__ offs) {
    __shared__ int sm[256];
    int t = threadIdx.x;
    int v = (t < SCAN_BLOCKS) ? P[t] : 0;
    sm[t] = v; __syncthreads();
    for (int o = 1; o < 256; o <<= 1) {
        int u = (t >= o) ? sm[t - o] : 0;
        __syncthreads();
        sm[t] += u;
        __syncthreads();
    }
    if (t < SCAN_BLOCKS) P[t] = sm[t] - v;  // exclusive tile bases
    if (t == 255) offs[N] = sm[255];        // total == E
}

__global__ __launch_bounds__(256) void scan3_kernel(int* __restrict__ offs,
                                                    const int* __restrict__ P) {
    int i = blockIdx.x * 256 + threadIdx.x;
    if (i < N) offs[i] += P[blockIdx.x];
}

__global__ __launch_bounds__(256) void scatter_kernel(const int* __restrict__ ei32,
                                                      const int* __restrict__ flag,
                                                      const int* __restrict__ offs,
                                                      int* __restrict__ cursor,
                                                      int* __restrict__ csr) {
    int i = blockIdx.x * 256 + threadIdx.x;
    int is64 = *flag;
    if (i < E) {
        int d = load_dst(ei32, is64, i);
        int p = atomicAdd(&cursor[d], 1);
        csr[offs[d] + p] = load_src(ei32, is64, i);
    }
}

// ---------------- chunk 0 = x (float4 row copy into strided out) ----------------

__global__ __launch_bounds__(256) void chunk0_kernel(const float* __restrict__ x,
                                                     float* __restrict__ out) {
    int i = blockIdx.x * 256 + threadIdx.x;   // over N*16 float4 groups
    if (i < N * 16) {
        int n = i >> 4, j = i & 15;
        float4 v = ((const float4*)x)[i];                 // x row: 256 B contiguous
        ((float4*)(out + (size_t)n * DOUT))[j] = v;       // 1280n bytes, 16B-aligned
    }
}

// ---------------- WL iteration: one wave per node, lane = feature ----------------
// Reads chunk c-1 from out (stride DOUT), writes chunk c. Rows are 256 B
// contiguous -> each gathered row is one coalesced wave load.

__global__ __launch_bounds__(256) void wl_iter_kernel(
    const float* __restrict__ xin,   // = out + (c-1)*D
    float* __restrict__ xout,        // = out + c*D
    const int* __restrict__ offs, const int* __restrict__ csr) {
    int w = blockIdx.x * 4 + (threadIdx.x >> 6);   // node id (4 waves / block)
    int lane = threadIdx.x & 63;                   // feature id
    if (w >= N) return;
    int beg = offs[w], end = offs[w + 1];
    float a0 = 0.f, a1 = 0.f, a2 = 0.f, a3 = 0.f;
    int e = beg;
    for (; e + 4 <= end; e += 4) {
        int s0 = csr[e + 0], s1 = csr[e + 1], s2 = csr[e + 2], s3 = csr[e + 3];
        a0 += xin[(size_t)s0 * DOUT + lane];
        a1 += xin[(size_t)s1 * DOUT + lane];
        a2 += xin[(size_t)s2 * DOUT + lane];
        a3 += xin[(size_t)s3 * DOUT + lane];
    }
    for (; e < end; ++e) a0 += xin[(size_t)csr[e] * DOUT + lane];
    float acc = (a0 + a1) + (a2 + a3);
    int deg = end - beg;
    float self = xin[(size_t)w * DOUT + lane];
    float inv = (deg > 0) ? 0.5f / (float)deg : 0.0f;   // deg==0 -> mean 0
    xout[(size_t)w * DOUT + lane] = 0.5f * self + inv * acc;
}

// ---------------- no-CSR fallback (tiny workspace): edge-parallel atomics ----

__global__ __launch_bounds__(256) void selfinit_kernel(const float* __restrict__ prev,
                                                       float* __restrict__ cur) {
    int i = blockIdx.x * 256 + threadIdx.x;   // N*D threads
    if (i < N * D) {
        int n = i >> 6, l = i & 63;
        cur[(size_t)n * DOUT + l] = 0.5f * prev[(size_t)n * DOUT + l];
    }
}

__global__ __launch_bounds__(256) void edge_atomic_kernel(const int* __restrict__ ei32,
                                                          const int* __restrict__ flag,
                                                          const int* __restrict__ cnt,
                                                          const float* __restrict__ prev,
                                                          float* __restrict__ cur) {
    int e = blockIdx.x * 4 + (threadIdx.x >> 6);
    int lane = threadIdx.x & 63;
    int is64 = *flag;
    if (e < E) {
        int s = load_src(ei32, is64, e);
        int d = load_dst(ei32, is64, e);
        float inv = 0.5f / (float)cnt[d];   // deg>=1 since this edge exists
        atomicAdd(&cur[(size_t)d * DOUT + lane], inv * prev[(size_t)s * DOUT + lane]);
    }
}

// ---------------- launch ----------------

extern "C" void kernel_launch(void* const* d_in, const int* in_sizes, int n_in,
                              void* d_out, int out_size, void* d_ws, size_t ws_size,
                              hipStream_t stream) {
    const float* x  = (const float*)d_in[0];
    const int* ei32 = (const int*)d_in[1];
    float* out = (float*)d_out;

    // workspace layout
    int* flag   = (int*)d_ws;            // 16 (padded)
    int* offs   = flag + 16;             // N+1
    int* P      = offs + (N + 1);        // 256
    int* cursor = P + 256;               // N
    int* csr    = cursor + N;            // E
    size_t need_csr = (size_t)(16 + N + 1 + 256 + N + E) * 4;

    dim3 b256(256);
    dim3 gE((E + 255) / 256);
    dim3 gScan(SCAN_BLOCKS);
    dim3 gIter((N + 3) / 4);

    detect_kernel<<<1, 64, 0, stream>>>(ei32, flag);

    // chunk 0 = x
    chunk0_kernel<<<dim3((N * 16 + 255) / 256), b256, 0, stream>>>(x, out);

    if (ws_size >= need_csr) {
        // ---- CSR build: histogram -> exclusive scan -> bucket scatter ----
        hipMemsetAsync(cursor, 0, (size_t)N * 4, stream);
        hist_kernel<<<gE, b256, 0, stream>>>(ei32, flag, cursor);
        scan1_kernel<<<gScan, b256, 0, stream>>>(cursor, offs, P);
        scan2_kernel<<<1, b256, 0, stream>>>(P, offs);
        scan3_kernel<<<gScan, b256, 0, stream>>>(offs, P);
        hipMemsetAsync(cursor, 0, (size_t)N * 4, stream);
        scatter_kernel<<<gE, b256, 0, stream>>>(ei32, flag, offs, cursor, csr);

        // ---- 4 WL iterations chained through out chunks ----
        for (int c = 1; c <= 4; ++c) {
            wl_iter_kernel<<<gIter, b256, 0, stream>>>(
                out + (size_t)(c - 1) * D, out + (size_t)c * D, offs, csr);
        }
    } else {
        // ---- tiny-workspace fallback: degree histogram + edge-parallel atomics
        int* cnt = flag + 16;            // N ints
        hipMemsetAsync(cnt, 0, (size_t)N * 4, stream);
        hist_kernel<<<gE, b256, 0, stream>>>(ei32, flag, cnt);
        for (int c = 1; c <= 4; ++c) {
            const float* prev = out + (size_t)(c - 1) * D;
            float* cur = out + (size_t)c * D;
            selfinit_kernel<<<dim3((N * D + 255) / 256), b256, 0, stream>>>(prev, cur);
            edge_atomic_kernel<<<dim3((E + 3) / 4), b256, 0, stream>>>(ei32, flag, cnt, prev, cur);
        }
    }
}

// Round 4
// 268.294 us; speedup vs baseline: 1.2095x; 1.2095x over previous
//
#include <hip/hip_runtime.h>

// FLOAT32 problem. N=50000 nodes, E=800000 edges, D=64 feats, out = [N, 5*D].
constexpr int N = 50000;
constexpr int E = 800000;
constexpr int D = 64;
constexpr int DOUT = 320;
constexpr int SCAN_BLOCKS = (N + 255) / 256;   // 196

// ---------------- index dtype detection (int64 vs int32) ----------------
__global__ void detect_kernel(const int* __restrict__ ei32, int* __restrict__ flag) {
    if (blockIdx.x == 0 && threadIdx.x == 0) {
        int s = 0;
        for (int k = 0; k < 128; ++k) s |= ei32[2 * k + 1];
        *flag = (s == 0) ? 1 : 0;
    }
}

__device__ __forceinline__ int load_src(const int* ei32, int is64, int i) {
    return is64 ? ei32[2 * i] : ei32[i];
}
__device__ __forceinline__ int load_dst(const int* ei32, int is64, int i) {
    return is64 ? ei32[2 * (E + i)] : ei32[E + i];
}

// ---------------- CSR build: one atomic pass (hist + rank), scan, place ----

__global__ __launch_bounds__(256) void hist_rank_kernel(const int* __restrict__ ei32,
                                                        const int* __restrict__ flag,
                                                        int* __restrict__ cnt,
                                                        int* __restrict__ rank) {
    int i = blockIdx.x * 256 + threadIdx.x;
    int is64 = *flag;
    if (i < E) rank[i] = atomicAdd(&cnt[load_dst(ei32, is64, i)], 1);
}

__global__ __launch_bounds__(256) void hist_kernel(const int* __restrict__ ei32,
                                                   const int* __restrict__ flag,
                                                   int* __restrict__ cnt) {
    int i = blockIdx.x * 256 + threadIdx.x;
    int is64 = *flag;
    if (i < E) atomicAdd(&cnt[load_dst(ei32, is64, i)], 1);
}

__global__ __launch_bounds__(256) void scan1_kernel(const int* __restrict__ cnt,
                                                    int* __restrict__ offs,
                                                    int* __restrict__ P) {
    __shared__ int sm[256];
    int t = threadIdx.x;
    int i = blockIdx.x * 256 + t;
    int v = (i < N) ? cnt[i] : 0;
    sm[t] = v; __syncthreads();
    for (int o = 1; o < 256; o <<= 1) {
        int u = (t >= o) ? sm[t - o] : 0;
        __syncthreads();
        sm[t] += u;
        __syncthreads();
    }
    if (i < N) offs[i] = sm[t] - v;         // tile-local exclusive
    if (t == 255) P[blockIdx.x] = sm[255];  // tile total
}

__global__ __launch_bounds__(256) void scan2_kernel(int* __restrict__ P,
                                                    int* __restrict__ offs) {
    __shared__ int sm[256];
    int t = threadIdx.x;
    int v = (t < SCAN_BLOCKS) ? P[t] : 0;
    sm[t] = v; __syncthreads();
    for (int o = 1; o < 256; o <<= 1) {
        int u = (t >= o) ? sm[t - o] : 0;
        __syncthreads();
        sm[t] += u;
        __syncthreads();
    }
    if (t < SCAN_BLOCKS) P[t] = sm[t] - v;  // exclusive tile bases
    if (t == 255) offs[N] = sm[255];        // total == E
}

__global__ __launch_bounds__(256) void scan3_kernel(int* __restrict__ offs,
                                                    const int* __restrict__ P) {
    int i = blockIdx.x * 256 + threadIdx.x;
    if (i < N) offs[i] += P[blockIdx.x];
}

__global__ __launch_bounds__(256) void place_kernel(const int* __restrict__ ei32,
                                                    const int* __restrict__ flag,
                                                    const int* __restrict__ offs,
                                                    const int* __restrict__ rank,
                                                    int* __restrict__ csr) {
    int i = blockIdx.x * 256 + threadIdx.x;
    int is64 = *flag;
    if (i < E) {
        int d = load_dst(ei32, is64, i);
        csr[offs[d] + rank[i]] = load_src(ei32, is64, i);  // no atomic
    }
}

// legacy single-pass scatter (used only if ws too small for rank[])
__global__ __launch_bounds__(256) void scatter_kernel(const int* __restrict__ ei32,
                                                      const int* __restrict__ flag,
                                                      const int* __restrict__ offs,
                                                      int* __restrict__ cursor,
                                                      int* __restrict__ csr) {
    int i = blockIdx.x * 256 + threadIdx.x;
    int is64 = *flag;
    if (i < E) {
        int d = load_dst(ei32, is64, i);
        int p = atomicAdd(&cursor[d], 1);
        csr[offs[d] + p] = load_src(ei32, is64, i);
    }
}

// ---------------- chunk 0 = x (float4 row copy into strided out) ------------

__global__ __launch_bounds__(256) void chunk0_kernel(const float* __restrict__ x,
                                                     float* __restrict__ out) {
    int i = blockIdx.x * 256 + threadIdx.x;   // over N*16 float4 groups
    if (i < N * 16) {
        int n = i >> 4, j = i & 15;
        float4 v = ((const float4*)x)[i];
        ((float4*)(out + (size_t)n * DOUT))[j] = v;
    }
}

// ---------------- WL iteration: one wave per node, float4 gather ------------
// Wave layout: 4 subgroups of 16 lanes. Subgroup g handles neighbors
// beg+g, beg+g+4, ... ; lane (g, fi) loads float4 at row*DOUT + fi*4.
// One global_load_dwordx4 covers 4 neighbor rows (1 KiB/wave/instr), 4x fewer
// VMEM instructions than the scalar-dword version. Shuffle-xor folds groups.

__global__ __launch_bounds__(256) void wl_iter_kernel(
    const float* __restrict__ xin,   // = out + (c-1)*D
    float* __restrict__ xout,        // = out + c*D
    const int* __restrict__ offs, const int* __restrict__ csr) {
    int w = blockIdx.x * 4 + (threadIdx.x >> 6);   // node id (4 waves/block)
    if (w >= N) return;
    int lane = threadIdx.x & 63;
    int g = lane >> 4;        // neighbor subgroup 0..3
    int fi = lane & 15;       // float4 slot within the 64-feat row
    int beg = offs[w], end = offs[w + 1];

    float4 a0 = make_float4(0.f, 0.f, 0.f, 0.f);
    float4 a1 = make_float4(0.f, 0.f, 0.f, 0.f);
    int e = beg + g;
    for (; e + 4 < end; e += 8) {    // two independent 1KiB gathers in flight
        int s0 = csr[e], s1 = csr[e + 4];
        float4 v0 = *(const float4*)(xin + (size_t)s0 * DOUT + fi * 4);
        float4 v1 = *(const float4*)(xin + (size_t)s1 * DOUT + fi * 4);
        a0.x += v0.x; a0.y += v0.y; a0.z += v0.z; a0.w += v0.w;
        a1.x += v1.x; a1.y += v1.y; a1.z += v1.z; a1.w += v1.w;
    }
    if (e < end) {
        int s = csr[e];
        float4 v = *(const float4*)(xin + (size_t)s * DOUT + fi * 4);
        a0.x += v.x; a0.y += v.y; a0.z += v.z; a0.w += v.w;
    }
    float4 acc;
    acc.x = a0.x + a1.x; acc.y = a0.y + a1.y;
    acc.z = a0.z + a1.z; acc.w = a0.w + a1.w;

    // fold the 4 subgroups: lanes l, l^16, l^32, l^48 share the same fi
    acc.x += __shfl_xor(acc.x, 16); acc.y += __shfl_xor(acc.y, 16);
    acc.z += __shfl_xor(acc.z, 16); acc.w += __shfl_xor(acc.w, 16);
    acc.x += __shfl_xor(acc.x, 32); acc.y += __shfl_xor(acc.y, 32);
    acc.z += __shfl_xor(acc.z, 32); acc.w += __shfl_xor(acc.w, 32);

    int deg = end - beg;
    float inv = (deg > 0) ? 0.5f / (float)deg : 0.0f;   // deg==0 -> mean 0
    if (g == 0) {   // 16 lanes write the full 256 B row
        float4 s4 = *(const float4*)(xin + (size_t)w * DOUT + fi * 4);
        float4 r;
        r.x = 0.5f * s4.x + inv * acc.x;
        r.y = 0.5f * s4.y + inv * acc.y;
        r.z = 0.5f * s4.z + inv * acc.z;
        r.w = 0.5f * s4.w + inv * acc.w;
        *(float4*)(xout + (size_t)w * DOUT + fi * 4) = r;
    }
}

// ---------------- launch ----------------

extern "C" void kernel_launch(void* const* d_in, const int* in_sizes, int n_in,
                              void* d_out, int out_size, void* d_ws, size_t ws_size,
                              hipStream_t stream) {
    const float* x  = (const float*)d_in[0];
    const int* ei32 = (const int*)d_in[1];
    float* out = (float*)d_out;

    // workspace layout (rank path)
    int* flag = (int*)d_ws;          // 16 (padded)
    int* cnt  = flag + 16;           // N
    int* offs = cnt + N;             // N+1
    int* P    = offs + (N + 1);      // 256
    int* rank = P + 256;             // E
    int* csrA = rank + E;            // E
    size_t need_rank = (size_t)(16 + N + N + 1 + 256 + E + E) * 4;   // ~6.8 MB
    size_t need_csr  = (size_t)(16 + N + N + 1 + 256 + E) * 4;       // ~3.6 MB

    dim3 b256(256);
    dim3 gE((E + 255) / 256);
    dim3 gScan(SCAN_BLOCKS);
    dim3 gIter((N + 3) / 4);

    detect_kernel<<<1, 64, 0, stream>>>(ei32, flag);

    // chunk 0 = x
    chunk0_kernel<<<dim3((N * 16 + 255) / 256), b256, 0, stream>>>(x, out);

    int* csr;
    if (ws_size >= need_rank) {
        csr = csrA;
        hipMemsetAsync(cnt, 0, (size_t)N * 4, stream);
        hist_rank_kernel<<<gE, b256, 0, stream>>>(ei32, flag, cnt, rank);
        scan1_kernel<<<gScan, b256, 0, stream>>>(cnt, offs, P);
        scan2_kernel<<<1, b256, 0, stream>>>(P, offs);
        scan3_kernel<<<gScan, b256, 0, stream>>>(offs, P);
        place_kernel<<<gE, b256, 0, stream>>>(ei32, flag, offs, rank, csr);
    } else {
        // low-ws fallback: two-pass scatter, csr sits where rank would be
        csr = rank;
        int* cursor = cnt;
        hipMemsetAsync(cursor, 0, (size_t)N * 4, stream);
        hist_kernel<<<gE, b256, 0, stream>>>(ei32, flag, cursor);
        scan1_kernel<<<gScan, b256, 0, stream>>>(cursor, offs, P);
        scan2_kernel<<<1, b256, 0, stream>>>(P, offs);
        scan3_kernel<<<gScan, b256, 0, stream>>>(offs, P);
        hipMemsetAsync(cursor, 0, (size_t)N * 4, stream);
        scatter_kernel<<<gE, b256, 0, stream>>>(ei32, flag, offs, cursor, csr);
    }

    for (int c = 1; c <= 4; ++c) {
        wl_iter_kernel<<<gIter, b256, 0, stream>>>(
            out + (size_t)(c - 1) * D, out + (size_t)c * D, offs, csr);
    }
}

// Round 5
// 252.023 us; speedup vs baseline: 1.2876x; 1.0646x over previous
//
#include <hip/hip_runtime.h>

// FLOAT32 problem. N=50000 nodes, E=800000 edges, D=64 feats, out = [N, 5*D].
// Iterated state kept in a compact bf16 mirror (N x 64, ping-pong in ws) for
// half the gather traffic; fp32 chunks written to out; 0.5*self term read fp32.
constexpr int N = 50000;
constexpr int E = 800000;
constexpr int D = 64;
constexpr int DOUT = 320;
constexpr int SCAN_BLOCKS = (N + 255) / 256;   // 196

// ---- bf16 helpers (RNE, manual — no dtype-header dependency) ----
__device__ __forceinline__ unsigned short f2bf(float f) {
    unsigned int u = __float_as_uint(f);
    unsigned int r = (u + 0x7fffu + ((u >> 16) & 1u)) >> 16;
    return (unsigned short)r;
}
__device__ __forceinline__ unsigned int pack2(float a, float b) {
    return (unsigned int)f2bf(a) | ((unsigned int)f2bf(b) << 16);
}
__device__ __forceinline__ float bflo(unsigned int u) { return __uint_as_float(u << 16); }
__device__ __forceinline__ float bfhi(unsigned int u) { return __uint_as_float(u & 0xFFFF0000u); }

// ---------------- index dtype detection (int64 vs int32) ----------------
__global__ void detect_kernel(const int* __restrict__ ei32, int* __restrict__ flag) {
    if (blockIdx.x == 0 && threadIdx.x == 0) {
        int s = 0;
        for (int k = 0; k < 128; ++k) s |= ei32[2 * k + 1];
        *flag = (s == 0) ? 1 : 0;
    }
}
__device__ __forceinline__ int load_src(const int* ei32, int is64, int i) {
    return is64 ? ei32[2 * i] : ei32[i];
}
__device__ __forceinline__ int load_dst(const int* ei32, int is64, int i) {
    return is64 ? ei32[2 * (E + i)] : ei32[E + i];
}

// ---------------- CSR build ----------------

__global__ __launch_bounds__(256) void hist_rank_kernel(const int* __restrict__ ei32,
                                                        const int* __restrict__ flag,
                                                        int* __restrict__ cnt,
                                                        int* __restrict__ rank) {
    int i = blockIdx.x * 256 + threadIdx.x;
    int is64 = *flag;
    if (i < E) rank[i] = atomicAdd(&cnt[load_dst(ei32, is64, i)], 1);
}

__global__ __launch_bounds__(256) void hist_kernel(const int* __restrict__ ei32,
                                                   const int* __restrict__ flag,
                                                   int* __restrict__ cnt) {
    int i = blockIdx.x * 256 + threadIdx.x;
    int is64 = *flag;
    if (i < E) atomicAdd(&cnt[load_dst(ei32, is64, i)], 1);
}

__global__ __launch_bounds__(256) void scan1_kernel(const int* __restrict__ cnt,
                                                    int* __restrict__ offs,
                                                    int* __restrict__ P) {
    __shared__ int sm[256];
    int t = threadIdx.x;
    int i = blockIdx.x * 256 + t;
    int v = (i < N) ? cnt[i] : 0;
    sm[t] = v; __syncthreads();
    for (int o = 1; o < 256; o <<= 1) {
        int u = (t >= o) ? sm[t - o] : 0;
        __syncthreads();
        sm[t] += u;
        __syncthreads();
    }
    if (i < N) offs[i] = sm[t] - v;
    if (t == 255) P[blockIdx.x] = sm[255];
}

__global__ __launch_bounds__(256) void scan2_kernel(int* __restrict__ P,
                                                    int* __restrict__ offs) {
    __shared__ int sm[256];
    int t = threadIdx.x;
    int v = (t < SCAN_BLOCKS) ? P[t] : 0;
    sm[t] = v; __syncthreads();
    for (int o = 1; o < 256; o <<= 1) {
        int u = (t >= o) ? sm[t - o] : 0;
        __syncthreads();
        sm[t] += u;
        __syncthreads();
    }
    if (t < SCAN_BLOCKS) P[t] = sm[t] - v;
    if (t == 255) offs[N] = sm[255];
}

__global__ __launch_bounds__(256) void scan3_kernel(int* __restrict__ offs,
                                                    const int* __restrict__ P) {
    int i = blockIdx.x * 256 + threadIdx.x;
    if (i < N) offs[i] += P[blockIdx.x];
}

__global__ __launch_bounds__(256) void place_kernel(const int* __restrict__ ei32,
                                                    const int* __restrict__ flag,
                                                    const int* __restrict__ offs,
                                                    const int* __restrict__ rank,
                                                    int* __restrict__ csr) {
    int i = blockIdx.x * 256 + threadIdx.x;
    int is64 = *flag;
    if (i < E) {
        int d = load_dst(ei32, is64, i);
        csr[offs[d] + rank[i]] = load_src(ei32, is64, i);
    }
}

__global__ __launch_bounds__(256) void scatter_kernel(const int* __restrict__ ei32,
                                                      const int* __restrict__ flag,
                                                      const int* __restrict__ offs,
                                                      int* __restrict__ cursor,
                                                      int* __restrict__ csr) {
    int i = blockIdx.x * 256 + threadIdx.x;
    int is64 = *flag;
    if (i < E) {
        int d = load_dst(ei32, is64, i);
        int p = atomicAdd(&cursor[d], 1);
        csr[offs[d] + p] = load_src(ei32, is64, i);
    }
}

// ------- convert: chunk0 (fp32 copy) + mirror0 (bf16) in one pass -------

__global__ __launch_bounds__(256) void convert_kernel(const float* __restrict__ x,
                                                      float* __restrict__ out,
                                                      unsigned int* __restrict__ mirror) {
    int i = blockIdx.x * 256 + threadIdx.x;   // over N*16 float4 groups
    if (i < N * 16) {
        int n = i >> 4, j = i & 15;
        float4 v = ((const float4*)x)[i];
        ((float4*)(out + (size_t)n * DOUT))[j] = v;
        // mirror row = 32 uints (64 bf16); float4 j -> words 2j, 2j+1
        uint2 m = make_uint2(pack2(v.x, v.y), pack2(v.z, v.w));
        ((uint2*)(mirror + (size_t)n * 32))[j] = m;
    }
}

// ---------------- WL iteration over bf16 mirror ----------------
// One wave per node. 8 subgroups x 8 lanes; lane (g, fi) loads 16 B (8 bf16)
// of neighbor row csr[e], e = beg+g, step 8 -> one uint4 gather covers 8
// neighbor rows per wave-instruction (1 KiB). fp32 accumulate, shfl-xor fold.

__global__ __launch_bounds__(256) void wl_iter_bf16_kernel(
    const unsigned int* __restrict__ min_,   // mirror in  (N*32 words)
    unsigned int* __restrict__ mout,         // mirror out (null on last iter)
    const float* __restrict__ self_in,       // out + (c-1)*D  (fp32 self term)
    float* __restrict__ xout,                // out + c*D
    const int* __restrict__ offs, const int* __restrict__ csr) {
    int w = blockIdx.x * 4 + (threadIdx.x >> 6);
    if (w >= N) return;
    int lane = threadIdx.x & 63;
    int g = lane >> 3;       // neighbor subgroup 0..7
    int fi = lane & 7;       // 16B slot in the 128B row
    int beg = offs[w], end = offs[w + 1];

    float a[8], b[8];
#pragma unroll
    for (int k = 0; k < 8; ++k) { a[k] = 0.f; b[k] = 0.f; }

#define ACC8(u, arr)                                                     \
    arr[0] += bflo(u.x); arr[1] += bfhi(u.x);                            \
    arr[2] += bflo(u.y); arr[3] += bfhi(u.y);                            \
    arr[4] += bflo(u.z); arr[5] += bfhi(u.z);                            \
    arr[6] += bflo(u.w); arr[7] += bfhi(u.w);

    int e = beg + g;
    for (; e + 8 < end; e += 16) {   // two independent 1KiB gathers in flight
        int s0 = csr[e], s1 = csr[e + 8];
        uint4 u0 = *(const uint4*)(min_ + (size_t)s0 * 32 + fi * 4);
        uint4 u1 = *(const uint4*)(min_ + (size_t)s1 * 32 + fi * 4);
        ACC8(u0, a); ACC8(u1, b);
    }
    if (e < end) {
        int s = csr[e];
        uint4 u = *(const uint4*)(min_ + (size_t)s * 32 + fi * 4);
        ACC8(u, a);
    }
#undef ACC8
#pragma unroll
    for (int k = 0; k < 8; ++k) {
        a[k] += b[k];
        a[k] += __shfl_xor(a[k], 8);
        a[k] += __shfl_xor(a[k], 16);
        a[k] += __shfl_xor(a[k], 32);
    }
    int deg = end - beg;
    float inv = (deg > 0) ? 0.5f / (float)deg : 0.0f;   // deg==0 -> mean 0
    if (g == 0) {   // 8 lanes own the full 64-feature row
        const float* srow = self_in + (size_t)w * DOUT + fi * 8;
        float4 s0 = *(const float4*)(srow);
        float4 s1 = *(const float4*)(srow + 4);
        float r0 = 0.5f * s0.x + inv * a[0];
        float r1 = 0.5f * s0.y + inv * a[1];
        float r2 = 0.5f * s0.z + inv * a[2];
        float r3 = 0.5f * s0.w + inv * a[3];
        float r4 = 0.5f * s1.x + inv * a[4];
        float r5 = 0.5f * s1.y + inv * a[5];
        float r6 = 0.5f * s1.z + inv * a[6];
        float r7 = 0.5f * s1.w + inv * a[7];
        float* drow = xout + (size_t)w * DOUT + fi * 8;
        *(float4*)(drow)     = make_float4(r0, r1, r2, r3);
        *(float4*)(drow + 4) = make_float4(r4, r5, r6, r7);
        if (mout) {
            uint4 m = make_uint4(pack2(r0, r1), pack2(r2, r3),
                                 pack2(r4, r5), pack2(r6, r7));
            *(uint4*)(mout + (size_t)w * 32 + fi * 4) = m;
        }
    }
}

// ---------------- fp32 fallback iteration (small ws) ----------------

__global__ __launch_bounds__(256) void wl_iter_kernel(
    const float* __restrict__ xin, float* __restrict__ xout,
    const int* __restrict__ offs, const int* __restrict__ csr) {
    int w = blockIdx.x * 4 + (threadIdx.x >> 6);
    if (w >= N) return;
    int lane = threadIdx.x & 63;
    int g = lane >> 4, fi = lane & 15;
    int beg = offs[w], end = offs[w + 1];
    float4 a0 = make_float4(0.f, 0.f, 0.f, 0.f);
    float4 a1 = make_float4(0.f, 0.f, 0.f, 0.f);
    int e = beg + g;
    for (; e + 4 < end; e += 8) {
        int s0 = csr[e], s1 = csr[e + 4];
        float4 v0 = *(const float4*)(xin + (size_t)s0 * DOUT + fi * 4);
        float4 v1 = *(const float4*)(xin + (size_t)s1 * DOUT + fi * 4);
        a0.x += v0.x; a0.y += v0.y; a0.z += v0.z; a0.w += v0.w;
        a1.x += v1.x; a1.y += v1.y; a1.z += v1.z; a1.w += v1.w;
    }
    if (e < end) {
        int s = csr[e];
        float4 v = *(const float4*)(xin + (size_t)s * DOUT + fi * 4);
        a0.x += v.x; a0.y += v.y; a0.z += v.z; a0.w += v.w;
    }
    float4 acc;
    acc.x = a0.x + a1.x; acc.y = a0.y + a1.y;
    acc.z = a0.z + a1.z; acc.w = a0.w + a1.w;
    acc.x += __shfl_xor(acc.x, 16); acc.y += __shfl_xor(acc.y, 16);
    acc.z += __shfl_xor(acc.z, 16); acc.w += __shfl_xor(acc.w, 16);
    acc.x += __shfl_xor(acc.x, 32); acc.y += __shfl_xor(acc.y, 32);
    acc.z += __shfl_xor(acc.z, 32); acc.w += __shfl_xor(acc.w, 32);
    int deg = end - beg;
    float inv = (deg > 0) ? 0.5f / (float)deg : 0.0f;
    if (g == 0) {
        float4 s4 = *(const float4*)(xin + (size_t)w * DOUT + fi * 4);
        float4 r;
        r.x = 0.5f * s4.x + inv * acc.x;
        r.y = 0.5f * s4.y + inv * acc.y;
        r.z = 0.5f * s4.z + inv * acc.z;
        r.w = 0.5f * s4.w + inv * acc.w;
        *(float4*)(xout + (size_t)w * DOUT + fi * 4) = r;
    }
}

__global__ __launch_bounds__(256) void chunk0_kernel(const float* __restrict__ x,
                                                     float* __restrict__ out) {
    int i = blockIdx.x * 256 + threadIdx.x;
    if (i < N * 16) {
        int n = i >> 4, j = i & 15;
        float4 v = ((const float4*)x)[i];
        ((float4*)(out + (size_t)n * DOUT))[j] = v;
    }
}

// ---------------- launch ----------------

extern "C" void kernel_launch(void* const* d_in, const int* in_sizes, int n_in,
                              void* d_out, int out_size, void* d_ws, size_t ws_size,
                              hipStream_t stream) {
    const float* x  = (const float*)d_in[0];
    const int* ei32 = (const int*)d_in[1];
    float* out = (float*)d_out;

    // workspace layout
    int* flag = (int*)d_ws;                  // 16 (padded)
    int* cnt  = flag + 16;                   // N
    int* offs = cnt + N;                     // N+1
    int* P    = offs + (N + 1);              // 256
    int* rank = P + 256;                     // E
    int* csrA = rank + E;                    // E
    unsigned int* mirA = (unsigned int*)(csrA + E);   // N*32 words (bf16 mirror)
    unsigned int* mirB = mirA + (size_t)N * 32;       // N*32 words
    size_t need_mirror = (size_t)(16 + N + N + 1 + 256 + 2 * E + 2 * N * 32) * 4; // ~19.6MB
    size_t need_rank   = (size_t)(16 + N + N + 1 + 256 + 2 * E) * 4;              // ~6.8MB

    dim3 b256(256);
    dim3 gE((E + 255) / 256);
    dim3 gScan(SCAN_BLOCKS);
    dim3 gIter((N + 3) / 4);
    dim3 gConv((N * 16 + 255) / 256);

    detect_kernel<<<1, 64, 0, stream>>>(ei32, flag);

    int* csr;
    if (ws_size >= need_rank) {
        csr = csrA;
        hipMemsetAsync(cnt, 0, (size_t)N * 4, stream);
        hist_rank_kernel<<<gE, b256, 0, stream>>>(ei32, flag, cnt, rank);
        scan1_kernel<<<gScan, b256, 0, stream>>>(cnt, offs, P);
        scan2_kernel<<<1, b256, 0, stream>>>(P, offs);
        scan3_kernel<<<gScan, b256, 0, stream>>>(offs, P);
        place_kernel<<<gE, b256, 0, stream>>>(ei32, flag, offs, rank, csr);
    } else {
        csr = rank;                          // csr where rank would be
        int* cursor = cnt;
        hipMemsetAsync(cursor, 0, (size_t)N * 4, stream);
        hist_kernel<<<gE, b256, 0, stream>>>(ei32, flag, cursor);
        scan1_kernel<<<gScan, b256, 0, stream>>>(cursor, offs, P);
        scan2_kernel<<<1, b256, 0, stream>>>(P, offs);
        scan3_kernel<<<gScan, b256, 0, stream>>>(offs, P);
        hipMemsetAsync(cursor, 0, (size_t)N * 4, stream);
        scatter_kernel<<<gE, b256, 0, stream>>>(ei32, flag, offs, cursor, csr);
    }

    if (ws_size >= need_mirror) {
        // bf16-mirror path: half the gather traffic, 8 rows per VMEM instr
        convert_kernel<<<gConv, b256, 0, stream>>>(x, out, mirA);
        wl_iter_bf16_kernel<<<gIter, b256, 0, stream>>>(
            mirA, mirB, out + 0 * D, out + 1 * D, offs, csr);
        wl_iter_bf16_kernel<<<gIter, b256, 0, stream>>>(
            mirB, mirA, out + 1 * D, out + 2 * D, offs, csr);
        wl_iter_bf16_kernel<<<gIter, b256, 0, stream>>>(
            mirA, mirB, out + 2 * D, out + 3 * D, offs, csr);
        wl_iter_bf16_kernel<<<gIter, b256, 0, stream>>>(
            mirB, (unsigned int*)nullptr, out + 3 * D, out + 4 * D, offs, csr);
    } else {
        chunk0_kernel<<<gConv, b256, 0, stream>>>(x, out);
        for (int c = 1; c <= 4; ++c) {
            wl_iter_kernel<<<gIter, b256, 0, stream>>>(
                out + (size_t)(c - 1) * D, out + (size_t)c * D, offs, csr);
        }
    }
}